// Round 8
// baseline (1715.721 us; speedup 1.0000x reference)
//
#include <hip/hip_runtime.h>
#include <math.h>

#define EPS 1e-6f

constexpr int BSZ = 16;    // batch * S
constexpr int DD  = 512;   // channels / S
constexpr int NN  = 4096;  // H*W
constexpr int RR  = 64;
constexpr int STEPS = 7;
constexpr int NS_B  = 8;   // BtB d-split blocks
constexpr int NS_C  = 32;  // CtC n-split blocks
constexpr int NS_N2 = 8;   // numer2 n-split partials

typedef __attribute__((ext_vector_type(8))) short short8;
typedef __attribute__((ext_vector_type(8))) unsigned short ushort8;
typedef __attribute__((ext_vector_type(4))) float f32x4;

__device__ __forceinline__ void fma4s(float4& a, const float4& b, float s) {
  a.x = fmaf(b.x, s, a.x); a.y = fmaf(b.y, s, a.y);
  a.z = fmaf(b.z, s, a.z); a.w = fmaf(b.w, s, a.w);
}
__device__ __forceinline__ void add4(float4& a, const float4& b) {
  a.x += b.x; a.y += b.y; a.z += b.z; a.w += b.w;
}
__device__ __forceinline__ unsigned short f2bf(float f) {
  unsigned u = __float_as_uint(f);
  return (unsigned short)((u + 0x7FFFu + ((u >> 16) & 1u)) >> 16);
}
__device__ __forceinline__ float bf2f(unsigned short h) {
  return __uint_as_float(((unsigned)h) << 16);
}
__device__ __forceinline__ f32x4 mfma16(short8 a, short8 b, f32x4 c) {
  return __builtin_amdgcn_mfma_f32_16x16x32_bf16(a, b, c, 0, 0, 0);
}

// async global->LDS, 16B per lane (fp32 fallback path)
__device__ __forceinline__ void gload16(const float* g, float* l) {
  __builtin_amdgcn_global_load_lds(
      (const __attribute__((address_space(1))) void*)g,
      (__attribute__((address_space(3))) void*)l, 16, 0, 0);
}

// ================= transpose + fp32->bf16 convert (hi, optional lo residual)
// src fp32 [b][R][C] -> dst bf16 [b][C][R].  Transpose happens on the LDS
// WRITE (scalar, stride-65 => <=2-way conflicts); reads are row-contiguous.
template <bool LO>
__global__ void __launch_bounds__(256) tcvt_kernel(const float* __restrict__ src,
                                                   unsigned short* __restrict__ dh,
                                                   unsigned short* __restrict__ dl,
                                                   int R, int C) {
  __shared__ float tileT[64 * 65];   // [src_col][src_row], stride 65
  const int b = blockIdx.z, c0 = blockIdx.x << 6, r0 = blockIdx.y << 6;
  const float* sp = src + (long long)b * R * C;
  const int t = threadIdx.x;
  #pragma unroll
  for (int i = 0; i < 4; ++i) {
    const int idx = t + (i << 8);
    const int row = idx >> 4, c4 = (idx & 15) << 2;
    const float4 v = *(const float4*)&sp[(long long)(r0 + row) * C + c0 + c4];
    tileT[(c4 + 0) * 65 + row] = v.x;
    tileT[(c4 + 1) * 65 + row] = v.y;
    tileT[(c4 + 2) * 65 + row] = v.z;
    tileT[(c4 + 3) * 65 + row] = v.w;
  }
  __syncthreads();
  const int orow = t >> 2, och = (t & 3) << 4;  // output row (=src col), 16 output cols
  ushort8 h0, h1, l0, l1;
  #pragma unroll
  for (int j = 0; j < 8; ++j) {
    const float v = tileT[orow * 65 + och + j];
    const unsigned short h = f2bf(v);
    h0[j] = h;
    if (LO) l0[j] = f2bf(v - bf2f(h));
  }
  #pragma unroll
  for (int j = 0; j < 8; ++j) {
    const float v = tileT[orow * 65 + och + 8 + j];
    const unsigned short h = f2bf(v);
    h1[j] = h;
    if (LO) l1[j] = f2bf(v - bf2f(h));
  }
  const long long ob = ((long long)b * C + c0 + orow) * R + r0 + och;
  *(ushort8*)&dh[ob] = h0;
  *(ushort8*)&dh[ob + 8] = h1;
  if (LO) { *(ushort8*)&dl[ob] = l0; *(ushort8*)&dl[ob + 8] = l1; }
}

// ================= flat fp32 -> bf16 hi/lo cast (no transpose)
__global__ void __launch_bounds__(256) casthl_kernel(const float* __restrict__ src,
                                                     unsigned short* __restrict__ dh,
                                                     unsigned short* __restrict__ dl,
                                                     long long n) {
  const long long i = ((long long)blockIdx.x * 256 + threadIdx.x) * 8;
  if (i >= n) return;
  const float4 a = *(const float4*)&src[i];
  const float4 c = *(const float4*)&src[i + 4];
  const float e[8] = {a.x, a.y, a.z, a.w, c.x, c.y, c.z, c.w};
  ushort8 h, lo;
  #pragma unroll
  for (int j = 0; j < 8; ++j) {
    h[j] = f2bf(e[j]);
    lo[j] = f2bf(e[j] - bf2f(h[j]));
  }
  *(ushort8*)&dh[i] = h;
  *(ushort8*)&dl[i] = lo;
}

// ================= MFMA fused numer + softmax (MODE0) / + coef update (MODE1)
// 128 thr = 2 waves; block = 32 n-rows x 64 r; wave owns 16 n-rows.
// numer = x_hi^T B~ + x_lo^T B~.  MODE1 tail: denom = cold @ G via MFMA
// (G symmetric => B-frag rows are G rows, k-contiguous), update applied in
// D-fragment positions.  No cross-wave coef sharing => no barrier needed.
template <int MODE>
__global__ void __launch_bounds__(128) fused_mfma_kernel(const unsigned short* __restrict__ xbTh,
                                                         const unsigned short* __restrict__ xbTl,
                                                         const unsigned short* __restrict__ BbT,
                                                         const float* __restrict__ btbp,
                                                         float* __restrict__ coef) {
  __shared__ unsigned short Gh[(MODE == 1) ? 64 * 72 : 8];
  __shared__ unsigned short Gl[(MODE == 1) ? 64 * 72 : 8];
  const int b  = blockIdx.y;
  const int n0 = blockIdx.x << 5;
  const int t  = threadIdx.x;
  const int w  = t >> 6;
  const int l  = t & 63;
  const int row16 = l & 15;
  const int koff  = (l >> 4) << 3;
  const int nrb   = n0 + (w << 4);          // wave's 16 rows

  const unsigned short* aph = xbTh + ((long long)b * NN + nrb + row16) * DD + koff;
  const unsigned short* apl = xbTl + ((long long)b * NN + nrb + row16) * DD + koff;
  const unsigned short* bpt = BbT  + ((long long)b * RR + row16) * DD + koff;

  f32x4 acc[4];
  #pragma unroll
  for (int rs = 0; rs < 4; ++rs) acc[rs] = (f32x4){0.f, 0.f, 0.f, 0.f};

  #pragma unroll
  for (int kt = 0; kt < 16; ++kt) {
    const int ko = kt << 5;
    const short8 ah = *(const short8*)&aph[ko];
    const short8 al = *(const short8*)&apl[ko];
    short8 bf[4];
    #pragma unroll
    for (int rs = 0; rs < 4; ++rs) bf[rs] = *(const short8*)&bpt[rs * 16 * DD + ko];
    #pragma unroll
    for (int rs = 0; rs < 4; ++rs) {
      acc[rs] = mfma16(ah, bf[rs], acc[rs]);
      acc[rs] = mfma16(al, bf[rs], acc[rs]);
    }
  }

  if constexpr (MODE == 0) {
    // softmax over r per n-row: in-lane over rs, then 16-lane shfl group
    #pragma unroll
    for (int j = 0; j < 4; ++j) {
      float m = fmaxf(fmaxf(acc[0][j], acc[1][j]), fmaxf(acc[2][j], acc[3][j]));
      m = fmaxf(m, __shfl_xor(m, 1));
      m = fmaxf(m, __shfl_xor(m, 2));
      m = fmaxf(m, __shfl_xor(m, 4));
      m = fmaxf(m, __shfl_xor(m, 8));
      float s = 0.f;
      #pragma unroll
      for (int rs = 0; rs < 4; ++rs) { acc[rs][j] = __expf(acc[rs][j] - m); s += acc[rs][j]; }
      s += __shfl_xor(s, 1); s += __shfl_xor(s, 2);
      s += __shfl_xor(s, 4); s += __shfl_xor(s, 8);
      const float inv = 1.f / s;
      #pragma unroll
      for (int rs = 0; rs < 4; ++rs) acc[rs][j] *= inv;
    }
    #pragma unroll
    for (int rs = 0; rs < 4; ++rs)
      #pragma unroll
      for (int j = 0; j < 4; ++j)
        coef[((long long)b * NN + nrb + ((l >> 4) << 2) + j) * RR + (rs << 4) + row16] = acc[rs][j];
  } else {
    // ---- build G = sum_sp BtB partials, as bf16 hi/lo in LDS (stride 72)
    for (int i = t; i < 1024; i += 128) {
      float4 s = make_float4(0.f, 0.f, 0.f, 0.f);
      #pragma unroll
      for (int sp = 0; sp < NS_B; ++sp)
        add4(s, ((const float4*)(btbp + ((long long)sp * BSZ + b) * 4096))[i]);
      const int k = i >> 4, c4 = (i & 15) << 2;
      const float se[4] = {s.x, s.y, s.z, s.w};
      #pragma unroll
      for (int e = 0; e < 4; ++e) {
        const unsigned short h = f2bf(se[e]);
        Gh[k * 72 + c4 + e] = h;
        Gl[k * 72 + c4 + e] = f2bf(se[e] - bf2f(h));
      }
    }
    __syncthreads();
    // ---- denom = cold @ G via MFMA (k = 64, 2 k-tiles); 3-term hi/lo
    const float* crow = coef + ((long long)b * NN + nrb + row16) * RR;
    f32x4 dn[4];
    #pragma unroll
    for (int rs = 0; rs < 4; ++rs) dn[rs] = (f32x4){0.f, 0.f, 0.f, 0.f};
    #pragma unroll
    for (int kt = 0; kt < 2; ++kt) {
      const int ko = (kt << 5) + koff;
      const float4 c0 = *(const float4*)&crow[ko];
      const float4 c1 = *(const float4*)&crow[ko + 4];
      const float ce[8] = {c0.x, c0.y, c0.z, c0.w, c1.x, c1.y, c1.z, c1.w};
      short8 ch, cl;
      #pragma unroll
      for (int j = 0; j < 8; ++j) {
        const unsigned short h = f2bf(ce[j]);
        ch[j] = (short)h;
        cl[j] = (short)f2bf(ce[j] - bf2f(h));
      }
      #pragma unroll
      for (int rs = 0; rs < 4; ++rs) {
        const short8 gh = *(const short8*)&Gh[((rs << 4) + row16) * 72 + ko];
        const short8 gl = *(const short8*)&Gl[((rs << 4) + row16) * 72 + ko];
        dn[rs] = mfma16(ch, gh, dn[rs]);
        dn[rs] = mfma16(cl, gh, dn[rs]);
        dn[rs] = mfma16(ch, gl, dn[rs]);
      }
    }
    // ---- multiplicative update in D-frag positions (element-owner unique)
    #pragma unroll
    for (int rs = 0; rs < 4; ++rs)
      #pragma unroll
      for (int j = 0; j < 4; ++j) {
        const long long idx =
            ((long long)b * NN + nrb + ((l >> 4) << 2) + j) * RR + (rs << 4) + row16;
        const float co = coef[idx];
        coef[idx] = co * acc[rs][j] / (dn[rs][j] + EPS);
      }
  }
}

// ================= MFMA numer2 partials: n2p[s][b][d][r] = sum_n x[d][n]*c~[n][r]
__global__ void __launch_bounds__(128) numer2_mfma_kernel(const float* __restrict__ X,
                                                          const unsigned short* __restrict__ cbT,
                                                          float* __restrict__ n2p) {
  const int b  = blockIdx.z;
  const int s  = blockIdx.y;
  const int d0 = blockIdx.x << 6;
  const int t  = threadIdx.x;
  const int w  = t >> 6;
  const int l  = t & 63;
  const int row16 = l & 15;
  const int koff  = (l >> 4) << 3;
  const int nbeg  = s * (NN / NS_N2);

  const float* xp = X + ((long long)b * DD + d0 + w * 32 + row16) * NN + nbeg + koff;
  const unsigned short* cp = cbT + ((long long)b * RR + row16) * NN + nbeg + koff;

  f32x4 acc[2][4];
  #pragma unroll
  for (int ds = 0; ds < 2; ++ds)
    #pragma unroll
    for (int rs = 0; rs < 4; ++rs) acc[ds][rs] = (f32x4){0.f, 0.f, 0.f, 0.f};

  #pragma unroll
  for (int kt = 0; kt < 16; ++kt) {
    const int ko = kt << 5;
    short8 ah[2], al[2], bf[4];
    #pragma unroll
    for (int ds = 0; ds < 2; ++ds) {
      const float4 v0 = *(const float4*)&xp[(long long)ds * 16 * NN + ko];
      const float4 v1 = *(const float4*)&xp[(long long)ds * 16 * NN + ko + 4];
      const float ve[8] = {v0.x, v0.y, v0.z, v0.w, v1.x, v1.y, v1.z, v1.w};
      #pragma unroll
      for (int j = 0; j < 8; ++j) {
        const unsigned short h = f2bf(ve[j]);
        ah[ds][j] = (short)h;
        al[ds][j] = (short)f2bf(ve[j] - bf2f(h));
      }
    }
    #pragma unroll
    for (int rs = 0; rs < 4; ++rs) bf[rs] = *(const short8*)&cp[(long long)rs * 16 * NN + ko];
    #pragma unroll
    for (int ds = 0; ds < 2; ++ds)
      #pragma unroll
      for (int rs = 0; rs < 4; ++rs) {
        acc[ds][rs] = mfma16(ah[ds], bf[rs], acc[ds][rs]);
        acc[ds][rs] = mfma16(al[ds], bf[rs], acc[ds][rs]);
      }
  }
  float* op = n2p + (((long long)s * BSZ + b) * DD + d0 + w * 32) * RR;
  #pragma unroll
  for (int ds = 0; ds < 2; ++ds)
    #pragma unroll
    for (int rs = 0; rs < 4; ++rs)
      #pragma unroll
      for (int j = 0; j < 4; ++j)
        op[(long long)(ds * 16 + ((l >> 4) << 2) + j) * RR + (rs << 4) + row16] = acc[ds][rs][j];
}

// ================= MFMA out: out[d][n] = sum_r B[d][r]*coef[n][r]
// Both operands r-contiguous -> direct MFMA, 3-term hi/lo.
__global__ void __launch_bounds__(256) out_mfma_kernel(const unsigned short* __restrict__ bDh,
                                                       const unsigned short* __restrict__ bDl,
                                                       const unsigned short* __restrict__ cNh,
                                                       const unsigned short* __restrict__ cNl,
                                                       float* __restrict__ out) {
  const int n0 = blockIdx.x << 6;
  const int d0 = blockIdx.y << 6;
  const int b  = blockIdx.z;
  const int t  = threadIdx.x;
  const int w  = t >> 6;
  const int l  = t & 63;
  const int row16 = l & 15;
  const int koff  = (l >> 4) << 3;

  const unsigned short* aph = bDh + ((long long)b * DD + d0 + (w << 4) + row16) * RR + koff;
  const unsigned short* apl = bDl + ((long long)b * DD + d0 + (w << 4) + row16) * RR + koff;
  const unsigned short* bph = cNh + ((long long)b * NN + n0 + row16) * RR + koff;
  const unsigned short* bpl = cNl + ((long long)b * NN + n0 + row16) * RR + koff;

  f32x4 acc[4];
  #pragma unroll
  for (int ns = 0; ns < 4; ++ns) acc[ns] = (f32x4){0.f, 0.f, 0.f, 0.f};

  #pragma unroll
  for (int kt = 0; kt < 2; ++kt) {
    const int ko = kt << 5;
    const short8 ah = *(const short8*)&aph[ko];
    const short8 al = *(const short8*)&apl[ko];
    #pragma unroll
    for (int ns = 0; ns < 4; ++ns) {
      const short8 bh = *(const short8*)&bph[(long long)ns * 16 * RR + ko];
      const short8 bl = *(const short8*)&bpl[(long long)ns * 16 * RR + ko];
      acc[ns] = mfma16(ah, bh, acc[ns]);
      acc[ns] = mfma16(al, bh, acc[ns]);
      acc[ns] = mfma16(ah, bl, acc[ns]);
    }
  }
  #pragma unroll
  for (int ns = 0; ns < 4; ++ns)
    #pragma unroll
    for (int j = 0; j < 4; ++j)
      out[((long long)b * DD + d0 + (w << 4) + ((l >> 4) << 2) + j) * NN +
          n0 + (ns << 4) + row16] = acc[ns][j];
}

// ================= Gram partials (unchanged)
__global__ void __launch_bounds__(256) gram_kernel(const float* __restrict__ M,
                                                   float* __restrict__ outp,
                                                   int rowsPerWave,
                                                   long long batchStride) {
  __shared__ float red[RR * RR];
  const int lane = threadIdx.x & 63;
  const int wid  = threadIdx.x >> 6;
  const int b    = blockIdx.y;
  const long long rowbase = (long long)(blockIdx.x * 4 + wid) * rowsPerWave;
  const float* Mp = M + (long long)b * batchStride + rowbase * RR;
  float acc[RR];
  #pragma unroll
  for (int k = 0; k < RR; ++k) acc[k] = 0.f;
  #pragma unroll 2
  for (int rr = 0; rr < rowsPerWave; ++rr) {
    const float v = Mp[(long long)rr * RR + lane];
    #pragma unroll
    for (int k = 0; k < RR; ++k) acc[k] = fmaf(__shfl(v, k), v, acc[k]);
  }
  for (int w = 0; w < 4; ++w) {
    if (wid == w) {
      if (w == 0) {
        #pragma unroll
        for (int k = 0; k < RR; ++k) red[k * RR + lane] = acc[k];
      } else {
        #pragma unroll
        for (int k = 0; k < RR; ++k) red[k * RR + lane] += acc[k];
      }
    }
    __syncthreads();
  }
  float* op = outp + ((long long)blockIdx.x * BSZ + b) * (RR * RR);
  for (int i = threadIdx.x; i < RR * RR; i += 256) op[i] = red[i];
}

// ================= fused CtC-sum + numer2-sum + bases update (unchanged)
__global__ void __launch_bounds__(256) bupdate_kernel(float* __restrict__ Bw,
                                                      const float* __restrict__ n2p,
                                                      const float* __restrict__ ctcp,
                                                      int ns2) {
  __shared__ float ct[4096];
  const int b  = blockIdx.y;
  const int d0 = blockIdx.x << 6;
  #pragma unroll
  for (int i = 0; i < 4; ++i) {
    const int w = threadIdx.x + (i << 8);
    float4 s = make_float4(0.f, 0.f, 0.f, 0.f);
    for (int sp = 0; sp < NS_C; ++sp)
      add4(s, ((const float4*)(ctcp + ((long long)sp * BSZ + b) * 4096))[w]);
    ((float4*)ct)[w] = s;
  }
  __syncthreads();
  const int d  = d0 + (threadIdx.x >> 2);
  const int rq = (threadIdx.x & 3) << 4;

  float4 ns[4];
  #pragma unroll
  for (int j = 0; j < 4; ++j) ns[j] = make_float4(0.f, 0.f, 0.f, 0.f);
  for (int s = 0; s < ns2; ++s) {
    const float4* p = (const float4*)&n2p[(((long long)s * BSZ + b) * DD + d) * RR + rq];
    #pragma unroll
    for (int j = 0; j < 4; ++j) add4(ns[j], p[j]);
  }
  const float4* brow = (const float4*)&Bw[((long long)b * DD + d) * RR];
  float4 dn[4];
  #pragma unroll
  for (int j = 0; j < 4; ++j) dn[j] = make_float4(0.f, 0.f, 0.f, 0.f);
  for (int q = 0; q < 16; ++q) {
    const float4 b4 = brow[q];
    const float4* c0 = (const float4*)&ct[(4 * q + 0) * 64 + rq];
    const float4* c1 = (const float4*)&ct[(4 * q + 1) * 64 + rq];
    const float4* c2 = (const float4*)&ct[(4 * q + 2) * 64 + rq];
    const float4* c3 = (const float4*)&ct[(4 * q + 3) * 64 + rq];
    #pragma unroll
    for (int j = 0; j < 4; ++j) {
      fma4s(dn[j], c0[j], b4.x); fma4s(dn[j], c1[j], b4.y);
      fma4s(dn[j], c2[j], b4.z); fma4s(dn[j], c3[j], b4.w);
    }
  }
  float4* bp = (float4*)&Bw[((long long)b * DD + d) * RR + rq];
  float4 bo[4];
  #pragma unroll
  for (int j = 0; j < 4; ++j) bo[j] = bp[j];
  __syncthreads();
  #pragma unroll
  for (int j = 0; j < 4; ++j) {
    float4 o;
    o.x = bo[j].x * ns[j].x / (dn[j].x + EPS);
    o.y = bo[j].y * ns[j].y / (dn[j].y + EPS);
    o.z = bo[j].z * ns[j].z / (dn[j].z + EPS);
    o.w = bo[j].w * ns[j].w / (dn[j].w + EPS);
    bp[j] = o;
  }
}

// ================= fp32 fallback kernels (round-6 path) =================

template <int MODE>
__global__ void __launch_bounds__(128) fused_coef_kernel(const float* __restrict__ X,
                                                         const float* __restrict__ Bw,
                                                         const float* __restrict__ btbp,
                                                         float* __restrict__ coef) {
  __shared__ float lds[8192];
  const int b    = blockIdx.y;
  const int n0   = blockIdx.x << 6;
  const int t    = threadIdx.x;
  const int wid  = t >> 6;
  const int lane = t & 63;
  const int rgrp = t & 7;
  const int ngrp = t >> 3;
  const int nl   = ngrp << 2;
  const int r0   = rgrp << 3;
  const float* Xp = X  + (long long)b * DD * NN + n0;
  const float* Bp = Bw + (long long)b * DD * RR;

  float4 acc[4][2];
  #pragma unroll
  for (int i = 0; i < 4; ++i) { acc[i][0] = make_float4(0,0,0,0); acc[i][1] = make_float4(0,0,0,0); }

  auto stage = [&](int buf, int d0) {
    float* xd = lds + (buf << 11);
    float* bd = lds + 4096 + (buf << 11);
    const int rsub = lane >> 4;
    const int c4   = (lane & 15) << 2;
    #pragma unroll
    for (int j = 0; j < 4; ++j) {
      const int q   = (wid << 2) + j;
      const int row = (q << 2) + rsub;
      gload16(&Xp[(long long)(d0 + row) * NN + c4], xd + (q << 8));
      gload16(&Bp[(long long)(d0 + row) * RR + c4], bd + (q << 8));
    }
  };

  stage(0, 0);
  __syncthreads();
  for (int kt = 0; kt < 16; ++kt) {
    const int cur = kt & 1;
    if (kt + 1 < 16) stage(cur ^ 1, (kt + 1) << 5);
    const float* xs = lds + (cur << 11);
    const float* bs = lds + 4096 + (cur << 11);
    #pragma unroll 8
    for (int dd = 0; dd < 32; ++dd) {
      const float4 xv  = *(const float4*)&xs[(dd << 6) + nl];
      const float4 bv0 = *(const float4*)&bs[(dd << 6) + r0];
      const float4 bv1 = *(const float4*)&bs[(dd << 6) + r0 + 4];
      fma4s(acc[0][0], bv0, xv.x); fma4s(acc[0][1], bv1, xv.x);
      fma4s(acc[1][0], bv0, xv.y); fma4s(acc[1][1], bv1, xv.y);
      fma4s(acc[2][0], bv0, xv.z); fma4s(acc[2][1], bv1, xv.z);
      fma4s(acc[3][0], bv0, xv.w); fma4s(acc[3][1], bv1, xv.w);
    }
    __syncthreads();
  }

  if constexpr (MODE == 0) {
    #pragma unroll
    for (int i = 0; i < 4; ++i) {
      float4 a0 = acc[i][0], a1 = acc[i][1];
      float m = fmaxf(fmaxf(fmaxf(a0.x, a0.y), fmaxf(a0.z, a0.w)),
                      fmaxf(fmaxf(a1.x, a1.y), fmaxf(a1.z, a1.w)));
      m = fmaxf(m, __shfl_xor(m, 1));
      m = fmaxf(m, __shfl_xor(m, 2));
      m = fmaxf(m, __shfl_xor(m, 4));
      a0.x = __expf(a0.x - m); a0.y = __expf(a0.y - m);
      a0.z = __expf(a0.z - m); a0.w = __expf(a0.w - m);
      a1.x = __expf(a1.x - m); a1.y = __expf(a1.y - m);
      a1.z = __expf(a1.z - m); a1.w = __expf(a1.w - m);
      float s = a0.x + a0.y + a0.z + a0.w + a1.x + a1.y + a1.z + a1.w;
      s += __shfl_xor(s, 1); s += __shfl_xor(s, 2); s += __shfl_xor(s, 4);
      const float inv = 1.f / s;
      a0.x *= inv; a0.y *= inv; a0.z *= inv; a0.w *= inv;
      a1.x *= inv; a1.y *= inv; a1.z *= inv; a1.w *= inv;
      float* cp = coef + ((long long)b * NN + n0 + nl + i) * RR + r0;
      *(float4*)&cp[0] = a0;
      *(float4*)&cp[4] = a1;
    }
  } else {
    float4* G4  = (float4*)lds;
    float4* CO4 = (float4*)(lds + 4096);
    #pragma unroll
    for (int j = 0; j < 8; ++j) {
      const int wi = t + (j << 7);
      float4 ssum = make_float4(0,0,0,0);
      #pragma unroll
      for (int sp = 0; sp < NS_B; ++sp)
        add4(ssum, ((const float4*)(btbp + ((long long)sp * BSZ + b) * 4096))[wi]);
      G4[wi] = ssum;
    }
    const float4* cof4 = (const float4*)(coef + ((long long)b * NN + n0) * RR);
    #pragma unroll
    for (int j = 0; j < 8; ++j) {
      const int wi = t + (j << 7);
      const int row = wi >> 4, c4 = wi & 15;
      CO4[(row << 4) + (c4 ^ ((row >> 2) & 7))] = cof4[wi];
    }
    __syncthreads();
    const int g = ngrp & 7;
    float4 dn[4][2];
    #pragma unroll
    for (int i = 0; i < 4; ++i) { dn[i][0] = make_float4(0,0,0,0); dn[i][1] = make_float4(0,0,0,0); }
    #pragma unroll 4
    for (int kq = 0; kq < 16; ++kq) {
      float4 g0[4], g1[4];
      #pragma unroll
      for (int jj = 0; jj < 4; ++jj) {
        g0[jj] = G4[(((kq << 2) + jj) << 4) + (rgrp << 1)];
        g1[jj] = G4[(((kq << 2) + jj) << 4) + (rgrp << 1) + 1];
      }
      #pragma unroll
      for (int i = 0; i < 4; ++i) {
        const float4 cv = CO4[((nl + i) << 4) + (kq ^ g)];
        fma4s(dn[i][0], g0[0], cv.x); fma4s(dn[i][1], g1[0], cv.x);
        fma4s(dn[i][0], g0[1], cv.y); fma4s(dn[i][1], g1[1], cv.y);
        fma4s(dn[i][0], g0[2], cv.z); fma4s(dn[i][1], g1[2], cv.z);
        fma4s(dn[i][0], g0[3], cv.w); fma4s(dn[i][1], g1[3], cv.w);
      }
    }
    #pragma unroll
    for (int i = 0; i < 4; ++i) {
      const int row = nl + i;
      const float4 c0 = CO4[(row << 4) + ((rgrp << 1) ^ g)];
      const float4 c1 = CO4[(row << 4) + (((rgrp << 1) + 1) ^ g)];
      float4 o0, o1;
      o0.x = c0.x * acc[i][0].x / (dn[i][0].x + EPS);
      o0.y = c0.y * acc[i][0].y / (dn[i][0].y + EPS);
      o0.z = c0.z * acc[i][0].z / (dn[i][0].z + EPS);
      o0.w = c0.w * acc[i][0].w / (dn[i][0].w + EPS);
      o1.x = c1.x * acc[i][1].x / (dn[i][1].x + EPS);
      o1.y = c1.y * acc[i][1].y / (dn[i][1].y + EPS);
      o1.z = c1.z * acc[i][1].z / (dn[i][1].z + EPS);
      o1.w = c1.w * acc[i][1].w / (dn[i][1].w + EPS);
      float* cp = coef + ((long long)b * NN + n0 + row) * RR + r0;
      *(float4*)&cp[0] = o0;
      *(float4*)&cp[4] = o1;
    }
  }
}

__global__ void __launch_bounds__(128) numer2_kernel(const float* __restrict__ X,
                                                     const float* __restrict__ coef,
                                                     float* __restrict__ n2p) {
  __shared__ float lds[8192];
  const int b    = blockIdx.z;
  const int s    = blockIdx.y;
  const int d0   = blockIdx.x << 6;
  const int t    = threadIdx.x;
  const int wid  = t >> 6;
  const int lane = t & 63;
  const int rgrp = t & 7;
  const int dgrp = t >> 3;
  const int dl   = dgrp << 2;
  const int r0   = rgrp << 3;
  const int nbeg = s * (NN / NS_N2);
  const float* Xp = X + (long long)b * DD * NN + (long long)d0 * NN;
  const float* Cp = coef + (long long)b * NN * RR;

  float4 acc[4][2];
  #pragma unroll
  for (int i = 0; i < 4; ++i) { acc[i][0] = make_float4(0,0,0,0); acc[i][1] = make_float4(0,0,0,0); }

  auto stage = [&](int buf, int nb) {
    float* xd = lds + (buf << 11);
    float* cd = lds + 4096 + (buf << 11);
    {
      const int rsub = lane >> 3, c4 = lane & 7;
      #pragma unroll
      for (int j = 0; j < 4; ++j) {
        const int q   = (wid << 2) + j;
        const int row = (q << 3) + rsub;
        const int sc  = (c4 ^ ((row >> 2) & 7)) << 2;
        gload16(&Xp[(long long)row * NN + nb + sc], xd + (q << 8));
      }
    }
    {
      const int rsub = lane >> 4, c4 = (lane & 15) << 2;
      #pragma unroll
      for (int j = 0; j < 4; ++j) {
        const int q   = (wid << 2) + j;
        const int row = (q << 2) + rsub;
        gload16(&Cp[(long long)(nb + row) * RR + c4], cd + (q << 8));
      }
    }
  };

  stage(0, nbeg);
  __syncthreads();
  const int g = dgrp & 7;
  for (int kt = 0; kt < (NN / NS_N2) / 32; ++kt) {
    const int cur = kt & 1;
    if (kt + 1 < (NN / NS_N2) / 32) stage(cur ^ 1, nbeg + ((kt + 1) << 5));
    const float* xs = lds + (cur << 11);
    const float* cs = lds + 4096 + (cur << 11);
    #pragma unroll 8
    for (int nn = 0; nn < 32; ++nn) {
      const int col = ((((nn >> 2) ^ g) << 2) + (nn & 3));
      float xe[4];
      #pragma unroll
      for (int i = 0; i < 4; ++i) xe[i] = xs[((dl + i) << 5) + col];
      const float4 cv0 = *(const float4*)&cs[(nn << 6) + r0];
      const float4 cv1 = *(const float4*)&cs[(nn << 6) + r0 + 4];
      #pragma unroll
      for (int i = 0; i < 4; ++i) {
        fma4s(acc[i][0], cv0, xe[i]);
        fma4s(acc[i][1], cv1, xe[i]);
      }
    }
    __syncthreads();
  }
  #pragma unroll
  for (int i = 0; i < 4; ++i) {
    float* op = n2p + (((long long)s * BSZ + b) * DD + d0 + dl + i) * RR + r0;
    *(float4*)&op[0] = acc[i][0];
    *(float4*)&op[4] = acc[i][1];
  }
}

__global__ void __launch_bounds__(256) out_kernel(const float* __restrict__ Bw,
                                                  const float* __restrict__ coef,
                                                  float* __restrict__ out) {
  __shared__ float bt [64 * 68];
  __shared__ float ctl[64 * 68];
  const int n0 = blockIdx.x << 6;
  const int d0 = blockIdx.y << 6;
  const int b  = blockIdx.z;
  const int tx = threadIdx.x & 15;
  const int ty = threadIdx.x >> 4;
  for (int t = threadIdx.x; t < 1024; t += 256) {
    const int row = t >> 4, c4 = (t & 15) << 2;
    const float4 v = *(const float4*)&Bw[((long long)b * DD + d0 + row) * RR + c4];
    bt[(c4 + 0) * 68 + row] = v.x; bt[(c4 + 1) * 68 + row] = v.y;
    bt[(c4 + 2) * 68 + row] = v.z; bt[(c4 + 3) * 68 + row] = v.w;
  }
  for (int t = threadIdx.x; t < 1024; t += 256) {
    const int row = t >> 4, c4 = (t & 15) << 2;
    const float4 v = *(const float4*)&coef[((long long)b * NN + n0 + row) * RR + c4];
    ctl[(c4 + 0) * 68 + row] = v.x; ctl[(c4 + 1) * 68 + row] = v.y;
    ctl[(c4 + 2) * 68 + row] = v.z; ctl[(c4 + 3) * 68 + row] = v.w;
  }
  __syncthreads();
  float4 ai[4];
  #pragma unroll
  for (int i = 0; i < 4; ++i) ai[i] = make_float4(0.f, 0.f, 0.f, 0.f);
  #pragma unroll 8
  for (int r = 0; r < 64; ++r) {
    const float4 bv = *(const float4*)&bt [r * 68 + (ty << 2)];
    const float4 cv = *(const float4*)&ctl[r * 68 + (tx << 2)];
    fma4s(ai[0], cv, bv.x); fma4s(ai[1], cv, bv.y);
    fma4s(ai[2], cv, bv.z); fma4s(ai[3], cv, bv.w);
  }
  #pragma unroll
  for (int i = 0; i < 4; ++i)
    *(float4*)&out[((long long)b * DD + d0 + (ty << 2) + i) * NN + n0 + (tx << 2)] = ai[i];
}

extern "C" void kernel_launch(void* const* d_in, const int* in_sizes, int n_in,
                              void* d_out, int out_size, void* d_ws, size_t ws_size,
                              hipStream_t stream) {
  const float* x        = (const float*)d_in[0];
  const float* bases_in = (const float*)d_in[1];
  float* out = (float*)d_out;
  float* ws  = (float*)d_ws;

  float* coef    = ws;
  float* bases_w = coef + (long long)BSZ * NN * RR;
  float* btbp    = bases_w + (long long)BSZ * DD * RR;
  float* ctcp    = btbp + (long long)NS_B * BSZ * 4096;
  float* n2p     = ctcp + (long long)NS_C * BSZ * 4096;
  unsigned short* xbTh = (unsigned short*)(n2p + (long long)NS_N2 * BSZ * DD * RR);
  unsigned short* xbTl = xbTh + (long long)BSZ * NN * DD;
  unsigned short* BbT  = xbTl + (long long)BSZ * NN * DD;
  unsigned short* cbT  = BbT + (long long)BSZ * RR * DD;
  const long long need = (long long)((char*)(cbT + (long long)BSZ * RR * NN) - (char*)d_ws);

  // aliased into btbp/ctcp/n2p (dead after the final fused<1>)
  unsigned short* cNh = (unsigned short*)btbp;
  unsigned short* cNl = cNh + (long long)BSZ * NN * RR;
  unsigned short* bDh = cNl + (long long)BSZ * NN * RR;
  unsigned short* bDl = bDh + (long long)BSZ * DD * RR;

  const dim3 blk256(256);
  const dim3 blk128(128);

  hipMemcpyAsync(bases_w, bases_in, sizeof(float) * BSZ * DD * RR,
                 hipMemcpyDeviceToDevice, stream);

  if ((long long)ws_size >= need) {
    // ---------- bf16-MFMA path ----------
    tcvt_kernel<true><<<dim3(NN / 64, DD / 64, BSZ), blk256, 0, stream>>>(x, xbTh, xbTl, DD, NN);
    tcvt_kernel<false><<<dim3(1, DD / 64, BSZ), blk256, 0, stream>>>(bases_w, BbT, nullptr, DD, RR);
    fused_mfma_kernel<0><<<dim3(NN / 32, BSZ), blk128, 0, stream>>>(xbTh, xbTl, BbT, nullptr, coef);

    for (int it = 0; it < STEPS; ++it) {
      tcvt_kernel<false><<<dim3(1, DD / 64, BSZ), blk256, 0, stream>>>(bases_w, BbT, nullptr, DD, RR);
      gram_kernel<<<dim3(NS_B, BSZ), blk256, 0, stream>>>(bases_w, btbp, DD / (NS_B * 4),
                                                          (long long)DD * RR);
      fused_mfma_kernel<1><<<dim3(NN / 32, BSZ), blk128, 0, stream>>>(xbTh, xbTl, BbT, btbp, coef);
      tcvt_kernel<false><<<dim3(1, NN / 64, BSZ), blk256, 0, stream>>>(coef, cbT, nullptr, NN, RR);
      gram_kernel<<<dim3(NS_C, BSZ), blk256, 0, stream>>>(coef, ctcp, NN / (NS_C * 4),
                                                          (long long)NN * RR);
      numer2_mfma_kernel<<<dim3(DD / 64, NS_N2, BSZ), blk128, 0, stream>>>(x, cbT, n2p);
      bupdate_kernel<<<dim3(DD / 64, BSZ), blk256, 0, stream>>>(bases_w, n2p, ctcp, NS_N2);
    }
    // compute_coef: one extra coef update with final bases
    tcvt_kernel<false><<<dim3(1, DD / 64, BSZ), blk256, 0, stream>>>(bases_w, BbT, nullptr, DD, RR);
    gram_kernel<<<dim3(NS_B, BSZ), blk256, 0, stream>>>(bases_w, btbp, DD / (NS_B * 4),
                                                        (long long)DD * RR);
    fused_mfma_kernel<1><<<dim3(NN / 32, BSZ), blk128, 0, stream>>>(xbTh, xbTl, BbT, btbp, coef);
    // final reconstruction via MFMA (cast kernels write into dead scratch)
    casthl_kernel<<<dim3(2048), blk256, 0, stream>>>(coef, cNh, cNl, (long long)BSZ * NN * RR);
    casthl_kernel<<<dim3(256), blk256, 0, stream>>>(bases_w, bDh, bDl, (long long)BSZ * DD * RR);
    out_mfma_kernel<<<dim3(NN / 64, DD / 64, BSZ), blk256, 0, stream>>>(bDh, bDl, cNh, cNl, out);
  } else {
    // ---------- fp32 fallback (round-6 path) ----------
    fused_coef_kernel<0><<<dim3(NN / 64, BSZ), blk128, 0, stream>>>(x, bases_w, nullptr, coef);
    for (int it = 0; it < STEPS; ++it) {
      gram_kernel<<<dim3(NS_B, BSZ), blk256, 0, stream>>>(bases_w, btbp, DD / (NS_B * 4),
                                                          (long long)DD * RR);
      fused_coef_kernel<1><<<dim3(NN / 64, BSZ), blk128, 0, stream>>>(x, bases_w, btbp, coef);
      gram_kernel<<<dim3(NS_C, BSZ), blk256, 0, stream>>>(coef, ctcp, NN / (NS_C * 4),
                                                          (long long)NN * RR);
      numer2_kernel<<<dim3(DD / 64, NS_N2, BSZ), blk128, 0, stream>>>(x, coef, n2p);
      bupdate_kernel<<<dim3(DD / 64, BSZ), blk256, 0, stream>>>(bases_w, n2p, ctcp, NS_N2);
    }
    gram_kernel<<<dim3(NS_B, BSZ), blk256, 0, stream>>>(bases_w, btbp, DD / (NS_B * 4),
                                                        (long long)DD * RR);
    fused_coef_kernel<1><<<dim3(NN / 64, BSZ), blk128, 0, stream>>>(x, bases_w, btbp, coef);
    out_kernel<<<dim3(NN / 64, DD / 64, BSZ), blk256, 0, stream>>>(bases_w, coef, out);
  }
}